// Round 14
// baseline (1975.936 us; speedup 1.0000x reference)
//
#include <hip/hip_runtime.h>

#define BATCH 64
#define TIN   49
#define NB    24
#define HID   384
#define SOUT  10
#define NGATE 5
#define FPAIR 5     // frame pairs (SOUT/2)
#define TILE  24    // 16-col tiles per cell

typedef __attribute__((ext_vector_type(4))) float f32x4;
typedef __attribute__((ext_vector_type(8))) short short8v;

__device__ __forceinline__ unsigned short f2bf(float f) {
    union { float f; unsigned u; } v; v.f = f;
    unsigned r = v.u + 0x7fffu + ((v.u >> 16) & 1u);   // round-nearest-even
    return (unsigned short)(r >> 16);
}
__device__ __forceinline__ float bf2f(unsigned short h) {
    union { unsigned u; float f; } v; v.u = ((unsigned)h) << 16; return v.f;
}

#define NW3_BLK 4320    // 48 cells * 5 gates * 3 mats * 6 kb(64-row spans)
#define NP_BLK  23040
#define NM_BLK  576

// ---------------------------------------------------------------------------
// Fused prologue: pack_w (sequential-stream + LDS transpose) + pack_p +
// init_means. wpack layout (short8 units):
//   [(cell*12+t32)*5+g][kc=36][pair=2][lane=64]
//   kc = m*12 + kb*2 + kc2; elem jj: B[k][col], k = kc%12*32+(lane>>4)*8+jj
//   within source m, col = t32*32 + pair*16 + (lane&15).
// ---------------------------------------------------------------------------
__global__ __launch_bounds__(256) void prologue_kernel(
    const float* __restrict__ U, const float* __restrict__ Wt,
    const float* __restrict__ Ws, const float* __restrict__ p,
    const float* __restrict__ hid, const float* __restrict__ cel,
    const float* __restrict__ gt,
    unsigned short* __restrict__ wpack, unsigned short* __restrict__ pb,
    unsigned short* __restrict__ hp_b, float* __restrict__ cp_f)
{
    __shared__ unsigned short tile[64][390];   // stride 195 dwords, gcd(195,32)=1
    int bx = blockIdx.x;
    if (bx < NW3_BLK) {
        int q = bx;
        int kb = q % 6; q /= 6;
        int m  = q % 3; q /= 3;
        int g  = q % 5; q /= 5;
        int cell = q;                                  // 0..47 (r*NB+n)
        const float* W = (m == 0) ? U : (m == 1) ? Wt : Ws;
        const float* src = W + ((size_t)(cell * NGATE + g) * HID + kb * 64) * HID;
        int tid = threadIdx.x;
#pragma unroll
        for (int i = 0; i < 24; ++i) {
            int c = tid + i * 256;
            int row = c / 96, c4 = (c % 96) * 4;       // 96 float4 per row
            float4 v = *(const float4*)(src + (size_t)row * HID + c4);
            tile[row][c4 + 0] = f2bf(v.x);
            tile[row][c4 + 1] = f2bf(v.y);
            tile[row][c4 + 2] = f2bf(v.z);
            tile[row][c4 + 3] = f2bf(v.w);
        }
        __syncthreads();
        int lane = tid & 63, grp = tid >> 6;
#pragma unroll
        for (int uu = 0; uu < 12; ++uu) {
            int unit = grp * 12 + uu;                  // 0..47
            int pair = unit & 1, kc2 = (unit >> 1) & 1, t32 = unit >> 2;
            int kl = kc2 * 32 + (lane >> 4) * 8;
            int cl = t32 * 32 + pair * 16 + (lane & 15);
            unsigned short o[8];
#pragma unroll
            for (int jj = 0; jj < 8; ++jj) o[jj] = tile[kl + jj][cl];
            int kc = m * 12 + kb * 2 + kc2;
            size_t dst = ((size_t)((cell * 12 + t32) * NGATE + g) * 72
                          + kc * 2 + pair) * 64 + lane;
            *(short8v*)(wpack + dst * 8) = *(const short8v*)o;
        }
    } else if (bx < NW3_BLK + NP_BLK) {
        // p f32 [B][SOUT][NB][H] -> bf16 [SOUT][NB][B][H]
        size_t idx = (size_t)(bx - NW3_BLK) * 256 + threadIdx.x;  // 5,898,240
        int h = (int)(idx % HID);
        size_t q = idx / HID;
        int b = (int)(q % BATCH); q /= BATCH;
        int n = (int)(q % NB); q /= NB;
        int f = (int)q;
        pb[idx] = f2bf(p[((size_t)(b * SOUT + f) * NB + n) * HID + h]);
    } else {
        // temporal means -> hp (bf16) + cp (f32), layout [r][n][b][h]
        int idx = (bx - NW3_BLK - NP_BLK) * 256 + threadIdx.x;    // 147,456
        const int total4 = NB * BATCH * HID / 4;
        if (idx >= total4) return;
        const int H4 = HID / 4;
        int h = (idx % H4) * 4;
        int b = (idx / H4) % BATCH;
        int n = idx / (H4 * BATCH);
        const int fs4 = NB * HID / 4;
        const float4* ph = (const float4*)(hid + ((size_t)b * TIN * NB + n) * HID + h);
        const float4* pc = (const float4*)(cel + ((size_t)b * TIN * NB + n) * HID + h);
        float sh[4] = {0,0,0,0}, sc[4] = {0,0,0,0};
        for (int t = 0; t < TIN; ++t) {
            float4 vh = ph[(size_t)t * fs4];
            float4 vc = pc[(size_t)t * fs4];
            sh[0] += vh.x; sh[1] += vh.y; sh[2] += vh.z; sh[3] += vh.w;
            sc[0] += vc.x; sc[1] += vc.y; sc[2] += vc.z; sc[3] += vc.w;
        }
        float4 g4 = *(const float4*)(gt + ((size_t)b * NB + n) * HID + h);
        const float* g_ = (const float*)&g4;
        unsigned short o0[4], o1[4];
        float c0[4];
#pragma unroll
        for (int j = 0; j < 4; ++j) {
            o0[j] = f2bf(sh[j] / TIN);
            o1[j] = f2bf((g_[j] + sh[j]) / (TIN + 1));
            c0[j] = sc[j] / TIN;
        }
        size_t base = (size_t)idx * 4;
        const size_t tot = (size_t)NB * BATCH * HID;
        *(uint2*)(hp_b + base)       = *(const uint2*)o0;
        *(uint2*)(hp_b + tot + base) = *(const uint2*)o1;
        *(float4*)(cp_f + base)       = make_float4(c0[0], c0[1], c0[2], c0[3]);
        *(float4*)(cp_f + tot + base) = make_float4(c0[0], c0[1], c0[2], c0[3]);
    }
}

// spatial boundary: mean over bones of the r=0 init states
__global__ void init_bounds_kernel(const unsigned short* __restrict__ hp_b,
                                   const float* __restrict__ cp_f,
                                   unsigned short* __restrict__ bh_b,
                                   float* __restrict__ bc_f) {
    int idx = blockIdx.x * blockDim.x + threadIdx.x;       // BATCH*HID
    if (idx >= BATCH * HID) return;
    float sh = 0.f, sc = 0.f;
    for (int n = 0; n < NB; ++n) {
        sh += bf2f(hp_b[(size_t)n * BATCH * HID + idx]);
        sc += cp_f[(size_t)n * BATCH * HID + idx];
    }
    bh_b[idx] = f2bf(sh / NB);
    bc_f[idx] = sc / NB;
}

__global__ void reset_scnt(int* scnt) {
    int i = blockIdx.x * 256 + threadIdx.x;
    if (i < 2 * NB * FPAIR) scnt[i] = 0;
}

// ---------------------------------------------------------------------------
// Super-cell frame-pair kernel. Dispatch sd = r0 super-cells on super-diag sd
// + r1 super-cells on sd-1 (all cross-cell deps come from the previous
// dispatch). Block = (super-cell, 16-col tile t), 960 thr = 15 waves
// (gate = wv%5, source m = wv/5). Two GEMM rounds (frames f0=2fp, f1=f0+1);
// WEIGHTS ARE READ ONCE PER SUPER-CELL: round B's re-read is intra-dispatch
// L2/L3-hot. Only new dep: frame f1 needs full h(f0) from the 24 sibling
// blocks -> per-super-cell release-counter + single-thread spin (all blocks
// co-resident: grid <= 240, 1 block/CU at 150KB LDS).
// ---------------------------------------------------------------------------
union SMemP {
    unsigned short A[3][64][392];        // 150,528 B
    float gl[3][NGATE][64][17];          // 65,280 B (aliases A; disjoint lifetime)
};

__global__ __launch_bounds__(960) void cell_pair_kernel(
    int sd, int A0,
    const unsigned short* __restrict__ pb,
    const unsigned short* __restrict__ wpack,
    const float* __restrict__ bias,
    const unsigned short* __restrict__ hp_b,
    const float* __restrict__ cp_f,
    const unsigned short* __restrict__ bh_b,
    const float* __restrict__ bc_f,
    unsigned short* __restrict__ h_st,   // [(r*NB+n)*SOUT+f][64][384] bf16
    float* __restrict__ c_st,            // same shape f32
    float* __restrict__ out,
    int* __restrict__ scnt)              // [2*NB*FPAIR]
{
    __shared__ SMemP sm;

    int y = (int)blockIdx.x / TILE;
    const int t = (int)blockIdx.x % TILE;
    int r, sdg;
    if (y < A0) { r = 0; sdg = sd; }
    else        { r = 1; sdg = sd - 1; y -= A0; }
    int lo = sdg - (FPAIR - 1); if (lo < 0) lo = 0;
    const int n  = lo + y;
    const int fp = sdg - n;
    const int f0 = fp * 2, f1 = f0 + 1;
    const int cell = r * NB + n;
    const int S = BATCH * HID;
    const int tid = threadIdx.x;
    const int wv = tid >> 6, gate = wv % NGATE, m = wv / NGATE, lane = tid & 63;

    auto hX = [&](int rr, int nn, int ff) -> size_t {
        return (size_t)((rr * NB + nn) * SOUT + ff) * S;
    };

    // ---- source pointers (all prior-dispatch except htB = sibling h(f0))
    const unsigned short *xbA, *htA, *hsA, *xbB, *htB, *hsB;
    const float *ctA, *csA, *csB;
    xbA = (r == 0) ? pb + (size_t)(f0 * NB + n) * S : h_st + hX(0, n, f0);
    htA = f0 ? h_st + hX(r, n, f0 - 1) : hp_b + (size_t)cell * S;
    hsA = n  ? h_st + hX(r, n - 1, f0) : bh_b;
    ctA = f0 ? c_st + hX(r, n, f0 - 1) : cp_f + (size_t)cell * S;
    csA = n  ? c_st + hX(r, n - 1, f0) : bc_f;
    xbB = (r == 0) ? pb + (size_t)(f1 * NB + n) * S : h_st + hX(0, n, f1);
    htB = h_st + hX(r, n, f0);
    hsB = n  ? h_st + hX(r, n - 1, f1) : bh_b;
    csB = n  ? c_st + hX(r, n - 1, f1) : bc_f;

    // weights: tile t -> t32 = t>>1, pair = t&1; per wave (gate, m) the j-th
    // K-step fragment sits at unit ((m*12+j)*2 + pair), stride 128 short8v.
    const short8v* wbm = (const short8v*)wpack
        + (size_t)((cell * 12 + (t >> 1)) * NGATE + gate) * (72 * 64)
        + (size_t)((m * 12) * 2 + (t & 1)) * 64 + lane;

    const int eb = tid & 63;
    const int ecq = (tid >> 6) & 3;
    const int colg = t * 16 + ecq * 4;

    float4 ctA4, csA4;
    if (tid < 256) {
        ctA4 = *(const float4*)(ctA + (size_t)eb * HID + colg);
        csA4 = *(const float4*)(csA + (size_t)eb * HID + colg);
    }

    // ---- staging helpers: per source 3072 16B chunks over 960 threads
    uint4 streg[12];
    auto LD1 = [&](const unsigned short* src, int slot) {
#pragma unroll
        for (int i = 0; i < 4; ++i) {
            int c = tid + i * 960;
            if (i < 3 || c < 3072) {
                int row = c / 48, cc = c - row * 48;
                streg[slot * 4 + i] = *(const uint4*)(src + (size_t)row * HID + cc * 8);
            }
        }
    };
    auto WR1 = [&](int s, int slot) {
#pragma unroll
        for (int i = 0; i < 4; ++i) {
            int c = tid + i * 960;
            if (i < 3 || c < 3072) {
                int row = c / 48, cc = c - row * 48;
                *(uint4*)&sm.A[s][row][cc * 8] = streg[slot * 4 + i];
            }
        }
    };

    const int arow = lane & 15, akg = (lane >> 4) * 8;

    // compute source m's K=384 into acc, then publish to gl[m][gate]
    auto COMPUTE_GL = [&]() {
        short8v bw0 = wbm[0], bw1 = wbm[128], bw2 = wbm[256];
        f32x4 acc[4];
#pragma unroll
        for (int q = 0; q < 4; ++q) acc[q] = (f32x4){0, 0, 0, 0};
#pragma unroll
        for (int j = 0; j < 12; ++j) {
            const int koff = j * 32 + akg;
            short8v a[4];
#pragma unroll
            for (int q = 0; q < 4; ++q)
                a[q] = *(const short8v*)&sm.A[m][arow + q * 16][koff];
            short8v bw = (j % 3 == 0) ? bw0 : (j % 3 == 1) ? bw1 : bw2;
#pragma unroll
            for (int q = 0; q < 4; ++q)
                acc[q] = __builtin_amdgcn_mfma_f32_16x16x32_bf16(a[q], bw, acc[q], 0, 0, 0);
            if (j < 9) {
                if (j % 3 == 0)      bw0 = wbm[(size_t)(j + 3) * 128];
                else if (j % 3 == 1) bw1 = wbm[(size_t)(j + 3) * 128];
                else                 bw2 = wbm[(size_t)(j + 3) * 128];
            }
        }
        __syncthreads();               // A reads done -> gl alias safe
#pragma unroll
        for (int q = 0; q < 4; ++q)
#pragma unroll
            for (int i = 0; i < 4; ++i)
                sm.gl[m][gate][q * 16 + (lane >> 4) * 4 + i][lane & 15] = acc[q][i];
        __syncthreads();               // gl visible
    };

    float chKeep[4];
    auto EPI = [&](const float* ct_, const float* cs_, int f, bool saveCt) {
        if (tid < 256) {
            const float* bb = bias + (size_t)cell * NGATE * HID + colg;
            size_t db = hX(r, n, f) + (size_t)eb * HID + colg;
            unsigned short hb4[4]; float hv4[4], ch4[4];
#pragma unroll
            for (int cc = 0; cc < 4; ++cc) {
                int c = ecq * 4 + cc;
                float gi  = sm.gl[0][0][eb][c] + sm.gl[1][0][eb][c] + sm.gl[2][0][eb][c] + bb[0 * HID + cc];
                float gfs = sm.gl[0][1][eb][c] + sm.gl[1][1][eb][c] + sm.gl[2][1][eb][c] + bb[1 * HID + cc];
                float gft = sm.gl[0][2][eb][c] + sm.gl[1][2][eb][c] + sm.gl[2][2][eb][c] + bb[2 * HID + cc];
                float go  = sm.gl[0][3][eb][c] + sm.gl[1][3][eb][c] + sm.gl[2][3][eb][c] + bb[3 * HID + cc];
                float gc  = sm.gl[0][4][eb][c] + sm.gl[1][4][eb][c] + sm.gl[2][4][eb][c] + bb[4 * HID + cc];
                float i_n = 1.f / (1.f + __expf(-gi));
                float f_s = 1.f / (1.f + __expf(-gfs));
                float f_t = 1.f / (1.f + __expf(-gft));
                float o_n = 1.f / (1.f + __expf(-go));
                float c_n = tanhf(gc);
                float ch  = i_n * c_n + f_t * ct_[cc] + f_s * cs_[cc];
                float hv  = o_n * tanhf(ch);
                hv4[cc] = hv; ch4[cc] = ch; hb4[cc] = f2bf(hv);
                if (saveCt) chKeep[cc] = ch;
            }
            *(uint2*)(h_st + db) = *(const uint2*)hb4;
            *(float4*)(c_st + db) = make_float4(ch4[0], ch4[1], ch4[2], ch4[3]);
            if (r == 1) {
                size_t o = ((size_t)(eb * SOUT + f) * NB + n) * HID + colg;
                *(float4*)(out + o) = make_float4(hv4[0], hv4[1], hv4[2], hv4[3]);
                *(float4*)(out + (size_t)BATCH * SOUT * NB * HID + o)
                    = make_float4(ch4[0], ch4[1], ch4[2], ch4[3]);
            }
        }
    };

    // ===================== round A (frame f0) =====================
    LD1(xbA, 0); LD1(htA, 1); LD1(hsA, 2);
    WR1(0, 0);  WR1(1, 1);  WR1(2, 2);
    __syncthreads();                   // A staged
    COMPUTE_GL();
    EPI((const float*)&ctA4, (const float*)&csA4, f0, true);
    __syncthreads();                   // epilogue done; h_st(f0) stores drained

    // ---- publish h(f0); prefetch prior-ready round-B sources; await siblings
    const int sci = (r * NB + n) * FPAIR + fp;
    if (tid == 0)
        __hip_atomic_fetch_add(scnt + sci, 1, __ATOMIC_RELEASE,
                               __HIP_MEMORY_SCOPE_AGENT);
    LD1(xbB, 0); LD1(hsB, 2);
    WR1(0, 0);  WR1(2, 2);
    float4 csB4;
    if (tid < 256) csB4 = *(const float4*)(csB + (size_t)eb * HID + colg);
    if (tid == 0) {
        while (__hip_atomic_load(scnt + sci, __ATOMIC_RELAXED,
                                 __HIP_MEMORY_SCOPE_AGENT) < TILE)
            __builtin_amdgcn_s_sleep(4);
        int z = __hip_atomic_load(scnt + sci, __ATOMIC_ACQUIRE,
                                  __HIP_MEMORY_SCOPE_AGENT);
        asm volatile("" :: "s"(z));
    }
    __syncthreads();                   // all siblings' h(f0) visible

    // ===================== round B (frame f1) =====================
    LD1(htB, 1); WR1(1, 1);
    __syncthreads();                   // A staged (B)
    COMPUTE_GL();
    EPI(chKeep, (const float*)&csB4, f1, false);
}

// ---------------------------------------------------------------------------
extern "C" void kernel_launch(void* const* d_in, const int* in_sizes, int n_in,
                              void* d_out, int out_size, void* d_ws, size_t ws_size,
                              hipStream_t stream) {
    const float* hid  = (const float*)d_in[0];
    const float* cel  = (const float*)d_in[1];
    const float* gt   = (const float*)d_in[2];
    // d_in[3] global_s_state: unused by the reference
    const float* p    = (const float*)d_in[4];
    const float* U    = (const float*)d_in[5];
    const float* Wt   = (const float*)d_in[6];
    const float* Ws   = (const float*)d_in[7];
    const float* bias = (const float*)d_in[8];
    float* out = (float*)d_out;

    char* cur_ = (char*)d_ws;
    auto carve = [&](size_t bytes) -> void* {
        void* r = cur_; cur_ += (bytes + 255) & ~(size_t)255; return r;
    };
    const size_t NPBH = (size_t)NB * BATCH * HID;
    unsigned short* wpack = (unsigned short*)carve((size_t)13271040 * 16); // 212 MB
    unsigned short* pb    = (unsigned short*)carve((size_t)SOUT * NB * BATCH * HID * 2);
    unsigned short* hp_b  = (unsigned short*)carve(2 * NPBH * 2);
    float*          cp_f  = (float*)carve(2 * NPBH * 4);
    unsigned short* bh_b  = (unsigned short*)carve((size_t)BATCH * HID * 2);
    float*          bc_f  = (float*)carve((size_t)BATCH * HID * 4);
    unsigned short* h_st  = (unsigned short*)carve((size_t)2 * NB * SOUT * BATCH * HID * 2);
    float*          c_st  = (float*)carve((size_t)2 * NB * SOUT * BATCH * HID * 4);
    int*            scnt  = (int*)carve(2 * NB * FPAIR * sizeof(int));

    reset_scnt<<<1, 256, 0, stream>>>(scnt);
    prologue_kernel<<<NW3_BLK + NP_BLK + NM_BLK, 256, 0, stream>>>(
        U, Wt, Ws, p, hid, cel, gt, wpack, pb, hp_b, cp_f);
    init_bounds_kernel<<<(BATCH * HID + 255) / 256, 256, 0, stream>>>(
        hp_b, cp_f, bh_b, bc_f);

    auto cnt = [](int sdg) {
        if (sdg < 0 || sdg > NB - 1 + FPAIR - 1) return 0;
        int lo = sdg - (FPAIR - 1); if (lo < 0) lo = 0;
        int hi = (sdg < NB - 1) ? sdg : NB - 1;
        return hi - lo + 1;
    };
    for (int sd = 0; sd <= NB + FPAIR - 1; ++sd) {     // 29 dispatches
        int A0 = cnt(sd);
        int A1 = cnt(sd - 1);
        if (A0 + A1 == 0) continue;
        cell_pair_kernel<<<TILE * (A0 + A1), 960, 0, stream>>>(
            sd, A0, pb, wpack, bias, hp_b, cp_f, bh_b, bc_f,
            h_st, c_st, out, scnt);
    }
}

// Round 15
// 1199.434 us; speedup vs baseline: 1.6474x; 1.6474x over previous
//
#include <hip/hip_runtime.h>

#define BATCH 64
#define TIN   49
#define NB    24
#define HID   384
#define SOUT  10
#define NGATE 5

typedef __attribute__((ext_vector_type(4))) float f32x4;
typedef __attribute__((ext_vector_type(8))) short short8v;

__device__ __forceinline__ unsigned short f2bf(float f) {
    union { float f; unsigned u; } v; v.f = f;
    unsigned r = v.u + 0x7fffu + ((v.u >> 16) & 1u);   // round-nearest-even
    return (unsigned short)(r >> 16);
}
__device__ __forceinline__ float bf2f(unsigned short h) {
    union { unsigned u; float f; } v; v.u = ((unsigned)h) << 16; return v.f;
}

// upfront prologue ranges: pack_w bones{0,1} + pack_p frames{0,1} + init_means
#define NWU_BLK 360     // 4 cells (0,1,24,25) x 90 tiles
#define NPU_BLK 4608    // 2 frame-slices x 2304
#define NMU_BLK 576
// deferred pack_w: bones 2..23 = 22 bones x 180 tiles = 3960 tiles,
// packed inside cell dispatches d=0..7 (540 tiles = 3 bones per dispatch).
#define PACK_TOT 3960
#define PB_BLKS  16     // hybrid pb-converter blocks per dispatch

// ---------------------------------------------------------------------------
// Upfront prologue: only what dispatch 0 needs.
// wpack layout (short8 units): [(cell*12+t32)*5+g][kc=36][pair=2][lane=64]
// ---------------------------------------------------------------------------
__global__ __launch_bounds__(256) void prologue_kernel(
    const float* __restrict__ U, const float* __restrict__ Wt,
    const float* __restrict__ Ws, const float* __restrict__ p,
    const float* __restrict__ hid, const float* __restrict__ cel,
    const float* __restrict__ gt,
    unsigned short* __restrict__ wpack, unsigned short* __restrict__ pb,
    unsigned short* __restrict__ hp_b, float* __restrict__ cp_f)
{
    __shared__ unsigned short tile[64][390];
    int bx = blockIdx.x;
    if (bx < NWU_BLK) {
        int c4i = bx / 90;
        int cell = (c4i < 2) ? c4i : 22 + c4i;         // {0,1,24,25}
        int sub = bx % 90;
        int kb = sub % 6, m = (sub / 6) % 3, g = sub / 18;
        const float* W = (m == 0) ? U : (m == 1) ? Wt : Ws;
        const float* src = W + ((size_t)(cell * NGATE + g) * HID + kb * 64) * HID;
        int tid = threadIdx.x;
#pragma unroll
        for (int i = 0; i < 24; ++i) {
            int c = tid + i * 256;
            int row = c / 96, c4 = (c % 96) * 4;
            float4 v = *(const float4*)(src + (size_t)row * HID + c4);
            tile[row][c4 + 0] = f2bf(v.x);
            tile[row][c4 + 1] = f2bf(v.y);
            tile[row][c4 + 2] = f2bf(v.z);
            tile[row][c4 + 3] = f2bf(v.w);
        }
        __syncthreads();
        int lane = tid & 63, grp = tid >> 6;
#pragma unroll
        for (int uu = 0; uu < 12; ++uu) {
            int unit = grp * 12 + uu;                  // 0..47
            int pair = unit & 1, kc2 = (unit >> 1) & 1, t32 = unit >> 2;
            int kl = kc2 * 32 + (lane >> 4) * 8;
            int cl = t32 * 32 + pair * 16 + (lane & 15);
            unsigned short o[8];
#pragma unroll
            for (int jj = 0; jj < 8; ++jj) o[jj] = tile[kl + jj][cl];
            int kc = m * 12 + kb * 2 + kc2;
            size_t dst = ((size_t)((cell * 12 + t32) * NGATE + g) * 72
                          + kc * 2 + pair) * 64 + lane;
            *(short8v*)(wpack + dst * 8) = *(const short8v*)o;
        }
    } else if (bx < NWU_BLK + NPU_BLK) {
        // p f32 [B][SOUT][NB][H] -> bf16 [SOUT][NB][B][H], frames 0..1 only
        size_t idx = (size_t)(bx - NWU_BLK) * 256 + threadIdx.x;
        int h = (int)(idx % HID);
        size_t q = idx / HID;
        int b = (int)(q % BATCH); q /= BATCH;
        int n = (int)(q % NB); q /= NB;
        int f = (int)q;                                // 0 or 1
        pb[idx] = f2bf(p[((size_t)(b * SOUT + f) * NB + n) * HID + h]);
    } else {
        // temporal means -> hp (bf16) + cp (f32), layout [r][n][b][h]
        int idx = (bx - NWU_BLK - NPU_BLK) * 256 + threadIdx.x;
        const int total4 = NB * BATCH * HID / 4;
        if (idx >= total4) return;
        const int H4 = HID / 4;
        int h = (idx % H4) * 4;
        int b = (idx / H4) % BATCH;
        int n = idx / (H4 * BATCH);
        const int fs4 = NB * HID / 4;
        const float4* ph = (const float4*)(hid + ((size_t)b * TIN * NB + n) * HID + h);
        const float4* pc = (const float4*)(cel + ((size_t)b * TIN * NB + n) * HID + h);
        float sh[4] = {0,0,0,0}, sc[4] = {0,0,0,0};
        for (int t = 0; t < TIN; ++t) {
            float4 vh = ph[(size_t)t * fs4];
            float4 vc = pc[(size_t)t * fs4];
            sh[0] += vh.x; sh[1] += vh.y; sh[2] += vh.z; sh[3] += vh.w;
            sc[0] += vc.x; sc[1] += vc.y; sc[2] += vc.z; sc[3] += vc.w;
        }
        float4 g4 = *(const float4*)(gt + ((size_t)b * NB + n) * HID + h);
        const float* g_ = (const float*)&g4;
        unsigned short o0[4], o1[4];
        float c0[4];
#pragma unroll
        for (int j = 0; j < 4; ++j) {
            o0[j] = f2bf(sh[j] / TIN);
            o1[j] = f2bf((g_[j] + sh[j]) / (TIN + 1));
            c0[j] = sc[j] / TIN;
        }
        size_t base = (size_t)idx * 4;
        const size_t tot = (size_t)NB * BATCH * HID;
        *(uint2*)(hp_b + base)       = *(const uint2*)o0;
        *(uint2*)(hp_b + tot + base) = *(const uint2*)o1;
        *(float4*)(cp_f + base)       = make_float4(c0[0], c0[1], c0[2], c0[3]);
        *(float4*)(cp_f + tot + base) = make_float4(c0[0], c0[1], c0[2], c0[3]);
    }
}

// spatial boundary: mean over bones of the r=0 init states
__global__ void init_bounds_kernel(const unsigned short* __restrict__ hp_b,
                                   const float* __restrict__ cp_f,
                                   unsigned short* __restrict__ bh_b,
                                   float* __restrict__ bc_f) {
    int idx = blockIdx.x * blockDim.x + threadIdx.x;       // BATCH*HID
    if (idx >= BATCH * HID) return;
    float sh = 0.f, sc = 0.f;
    for (int n = 0; n < NB; ++n) {
        sh += bf2f(hp_b[(size_t)n * BATCH * HID + idx]);
        sc += cp_f[(size_t)n * BATCH * HID + idx];
    }
    bh_b[idx] = f2bf(sh / NB);
    bc_f[idx] = sc / NB;
}

// ---------------------------------------------------------------------------
// Hybrid wavefront kernel. Block ranges:
//   [0, cellBlocks)                : r11 cell path (verbatim; t=bx%12, y=bx/12)
//   [cellBlocks, +packBlocks)      : deferred pack_w, 3 tiles per 960-block
//   [.., +pbBlocks)                : pack_p slice f = pbF
// Deadlines: bone n packed in dispatch <= n-1 (schedule: bones {2+3d..4+3d}
// at dispatch d); pb slice f produced at dispatch f-2. Dispatch boundaries
// provide the ordering -- no atomics.
// ---------------------------------------------------------------------------
union SMem {
    unsigned short A[3][64][392];        // 150,528 B (cell path)
    float gl[3][NGATE][64][35];          // aliases A after compute (cell path)
    unsigned short tile3[3][64][390];    // 149,760 B (pack path)
};

__global__ __launch_bounds__(960) void cell_fused_kernel(
    int d, int A0, int cellBlocks, int packBase, int packBlocks, int pbF,
    const float* __restrict__ U, const float* __restrict__ Wt,
    const float* __restrict__ Ws, const float* __restrict__ p,
    unsigned short* __restrict__ pb,
    unsigned short* __restrict__ wpack,
    const float* __restrict__ bias,
    const unsigned short* __restrict__ hp_b,
    const float* __restrict__ cp_f,
    const unsigned short* __restrict__ bh_b,
    const float* __restrict__ bc_f,
    unsigned short* __restrict__ h_sl,   // [par][r][NB][64][384] bf16
    float* __restrict__ c_sl,            // same shape f32
    float* __restrict__ out)
{
    __shared__ SMem sm;
    const int bx = (int)blockIdx.x;
    const int tid = threadIdx.x;

    if (bx >= cellBlocks) {
        if (bx < cellBlocks + packBlocks) {
            // ---------------- deferred pack_w path ----------------
            const int sub3 = tid >> 8;                 // 0..3 (3 active)
            const int stid = tid & 255;
            int pt = packBase + (bx - cellBlocks) * 3 + sub3;
            bool act = (sub3 < 3) && (pt < PACK_TOT);
            int cell = 0, g = 0, m = 0, kb = 0;
            const float* src = U;
            if (act) {
                int bone = 2 + pt / 180;
                int srem = pt % 180;
                cell = (srem / 90) * NB + bone;
                int sub = srem % 90;
                kb = sub % 6; m = (sub / 6) % 3; g = sub / 18;
                const float* W = (m == 0) ? U : (m == 1) ? Wt : Ws;
                src = W + ((size_t)(cell * NGATE + g) * HID + kb * 64) * HID;
            }
            if (act) {
#pragma unroll
                for (int i = 0; i < 24; ++i) {
                    int c = stid + i * 256;
                    int row = c / 96, c4 = (c % 96) * 4;
                    float4 v = *(const float4*)(src + (size_t)row * HID + c4);
                    sm.tile3[sub3][row][c4 + 0] = f2bf(v.x);
                    sm.tile3[sub3][row][c4 + 1] = f2bf(v.y);
                    sm.tile3[sub3][row][c4 + 2] = f2bf(v.z);
                    sm.tile3[sub3][row][c4 + 3] = f2bf(v.w);
                }
            }
            __syncthreads();
            if (act) {
                int lane = stid & 63, grp = stid >> 6;
#pragma unroll
                for (int uu = 0; uu < 12; ++uu) {
                    int unit = grp * 12 + uu;
                    int pair = unit & 1, kc2 = (unit >> 1) & 1, t32 = unit >> 2;
                    int kl = kc2 * 32 + (lane >> 4) * 8;
                    int cl = t32 * 32 + pair * 16 + (lane & 15);
                    unsigned short o[8];
#pragma unroll
                    for (int jj = 0; jj < 8; ++jj) o[jj] = sm.tile3[sub3][kl + jj][cl];
                    int kc = m * 12 + kb * 2 + kc2;
                    size_t dst = ((size_t)((cell * 12 + t32) * NGATE + g) * 72
                                  + kc * 2 + pair) * 64 + lane;
                    *(short8v*)(wpack + dst * 8) = *(const short8v*)o;
                }
            }
        } else {
            // ---------------- deferred pack_p path (slice pbF) ----------------
            const int f = pbF;
            int wbase = (bx - cellBlocks - packBlocks) * 960 + tid;
            for (int w = wbase; w < NB * BATCH * HID / 4; w += PB_BLKS * 960) {
                int l = w * 4;
                int n = l / (BATCH * HID);
                int rem = l - n * (BATCH * HID);
                int b = rem / HID;
                int h = rem - b * HID;
                float4 v = *(const float4*)(p + ((size_t)(b * SOUT + f) * NB + n) * HID + h);
                unsigned short o[4] = { f2bf(v.x), f2bf(v.y), f2bf(v.z), f2bf(v.w) };
                *(uint2*)(pb + (size_t)f * NB * BATCH * HID + l) = *(const uint2*)o;
            }
        }
        return;
    }

    // ======================= r11 cell path (verbatim) =======================
    const int t = bx % 12;               // 32-col tile, 0..11
    int y = bx / 12;
    int rstep, dg;
    if (y < A0) { rstep = 0; dg = d; }
    else        { rstep = 1; dg = d - 1; y -= A0; }
    int lo = dg - (SOUT - 1); if (lo < 0) lo = 0;
    const int n = lo + y;
    const int f = dg - n;
    const int cur = dg & 1, prv = cur ^ 1;
    const int wv   = tid >> 6;
    const int gate = wv % NGATE;
    const int m    = wv / NGATE;         // source 0..2
    const int lane = tid & 63;
    const int S = BATCH * HID;
    const int cell = rstep * NB + n;

    const unsigned short *xb, *htb, *hsb;
    const float *ctb, *csb;
    if (rstep == 0) {
        xb  = pb + (size_t)(f * NB + n) * S;
        htb = f ? h_sl + (size_t)((prv * 2 + 0) * NB + n) * S : hp_b + (size_t)n * S;
        hsb = n ? h_sl + (size_t)((prv * 2 + 0) * NB + n - 1) * S : bh_b;
        ctb = f ? c_sl + (size_t)((prv * 2 + 0) * NB + n) * S : cp_f + (size_t)n * S;
        csb = n ? c_sl + (size_t)((prv * 2 + 0) * NB + n - 1) * S : bc_f;
    } else {
        xb  = h_sl + (size_t)((cur * 2 + 0) * NB + n) * S;   // h0 of this cell
        htb = f ? h_sl + (size_t)((prv * 2 + 1) * NB + n) * S
                : hp_b + (size_t)(NB + n) * S;
        hsb = n ? h_sl + (size_t)((prv * 2 + 1) * NB + n - 1) * S : bh_b;
        ctb = f ? c_sl + (size_t)((prv * 2 + 1) * NB + n) * S
                : cp_f + (size_t)(NB + n) * S;
        csb = n ? c_sl + (size_t)((prv * 2 + 1) * NB + n - 1) * S : bc_f;
    }

    const short8v* wp = (const short8v*)wpack
        + (size_t)((cell * 12 + t) * NGATE + gate) * (36 * 2 * 64);
    const short8v* wbm = wp + (size_t)(m * 24) * 64 + lane;

    // ---- hoist epilogue cell-state loads
    const int eb = tid & 63;
    const int ecq = (tid >> 6) & 3;
    float4 cth[2], csh[2];
    if (tid < 256) {
#pragma unroll
        for (int h = 0; h < 2; ++h) {
            int colg = t * 32 + h * 16 + ecq * 4;
            cth[h] = *(const float4*)(ctb + (size_t)eb * HID + colg);
            csh[h] = *(const float4*)(csb + (size_t)eb * HID + colg);
        }
    }

    // ---- stage all 3 sources up-front: 3 x 3072 16B-chunks, 960 threads
    uint4 streg[12];
#pragma unroll
    for (int s = 0; s < 3; ++s) {
        const unsigned short* sp = (s == 0) ? xb : (s == 1) ? htb : hsb;
#pragma unroll
        for (int i = 0; i < 4; ++i) {
            int c = tid + i * 960;
            if (i < 3 || c < 3072) {
                int row = c / 48, cc = c - row * 48;
                streg[s * 4 + i] = *(const uint4*)(sp + (size_t)row * HID + cc * 8);
            }
        }
    }
#pragma unroll
    for (int s = 0; s < 3; ++s) {
#pragma unroll
        for (int i = 0; i < 4; ++i) {
            int c = tid + i * 960;
            if (i < 3 || c < 3072) {
                int row = c / 48, cc = c - row * 48;
                *(uint4*)&sm.A[s][row][cc * 8] = streg[s * 4 + i];
            }
        }
    }

    // ---- preload rolling B window (in flight across the barrier)
    short8v bufB[3][2];
#pragma unroll
    for (int j = 0; j < 3; ++j) {
        bufB[j][0] = wbm[(size_t)j * 128];
        bufB[j][1] = wbm[(size_t)j * 128 + 64];
    }
    __syncthreads();                      // barrier 1: A staged

    f32x4 acc[2][4];
#pragma unroll
    for (int pr = 0; pr < 2; ++pr)
#pragma unroll
        for (int q2 = 0; q2 < 4; ++q2) acc[pr][q2] = (f32x4){0, 0, 0, 0};

    const int arow = lane & 15;
    const int akg  = (lane >> 4) * 8;

#pragma unroll
    for (int j = 0; j < 12; ++j) {
        const int koff = j * 32 + akg;
        short8v a[4];
#pragma unroll
        for (int q2 = 0; q2 < 4; ++q2)
            a[q2] = *(const short8v*)&sm.A[m][arow + q2 * 16][koff];
        const int sl = j % 3;
#pragma unroll
        for (int q2 = 0; q2 < 4; ++q2) {
            acc[0][q2] = __builtin_amdgcn_mfma_f32_16x16x32_bf16(a[q2], bufB[sl][0], acc[0][q2], 0, 0, 0);
            acc[1][q2] = __builtin_amdgcn_mfma_f32_16x16x32_bf16(a[q2], bufB[sl][1], acc[1][q2], 0, 0, 0);
        }
        if (j < 9) {
            bufB[sl][0] = wbm[(size_t)(j + 3) * 128];
            bufB[sl][1] = wbm[(size_t)(j + 3) * 128 + 64];
        }
    }
    __syncthreads();                      // barrier 2: A reads done; gl may alias

    // ---- gate exchange: each wave owns plane gl[m][gate]
#pragma unroll
    for (int pr = 0; pr < 2; ++pr)
#pragma unroll
        for (int q2 = 0; q2 < 4; ++q2)
#pragma unroll
            for (int i = 0; i < 4; ++i)
                sm.gl[m][gate][q2 * 16 + (lane >> 4) * 4 + i][pr * 16 + (lane & 15)]
                    = acc[pr][q2][i];
    __syncthreads();                      // barrier 3: planes visible

    // ---- fused epilogue (256 threads)
    if (tid < 256) {
        size_t dbase = (size_t)((cur * 2 + rstep) * NB + n) * S + (size_t)eb * HID;
        const float* bbase = bias + (size_t)cell * NGATE * HID;
#pragma unroll
        for (int h = 0; h < 2; ++h) {
            int cloc = h * 16 + ecq * 4;
            int colg = t * 32 + cloc;
            const float* ct_ = (const float*)&cth[h];
            const float* cs_ = (const float*)&csh[h];
            float hv4[4], ch4[4];
            unsigned short hb4[4];
#pragma unroll
            for (int cc = 0; cc < 4; ++cc) {
                int c = cloc + cc;
                float gi  = sm.gl[0][0][eb][c] + sm.gl[1][0][eb][c] + sm.gl[2][0][eb][c] + bbase[0 * HID + colg + cc];
                float gfs = sm.gl[0][1][eb][c] + sm.gl[1][1][eb][c] + sm.gl[2][1][eb][c] + bbase[1 * HID + colg + cc];
                float gft = sm.gl[0][2][eb][c] + sm.gl[1][2][eb][c] + sm.gl[2][2][eb][c] + bbase[2 * HID + colg + cc];
                float go  = sm.gl[0][3][eb][c] + sm.gl[1][3][eb][c] + sm.gl[2][3][eb][c] + bbase[3 * HID + colg + cc];
                float gc  = sm.gl[0][4][eb][c] + sm.gl[1][4][eb][c] + sm.gl[2][4][eb][c] + bbase[4 * HID + colg + cc];
                float i_n = 1.f / (1.f + __expf(-gi));
                float f_s = 1.f / (1.f + __expf(-gfs));
                float f_t = 1.f / (1.f + __expf(-gft));
                float o_n = 1.f / (1.f + __expf(-go));
                float c_n = tanhf(gc);
                float ch  = i_n * c_n + f_t * ct_[cc] + f_s * cs_[cc];
                float hv  = o_n * tanhf(ch);
                hv4[cc] = hv; ch4[cc] = ch; hb4[cc] = f2bf(hv);
            }
            *(uint2*)(h_sl + dbase + colg) = *(const uint2*)hb4;
            *(float4*)(c_sl + dbase + colg) = make_float4(ch4[0], ch4[1], ch4[2], ch4[3]);
            if (rstep == 1) {
                size_t o = ((size_t)(eb * SOUT + f) * NB + n) * HID + colg;
                *(float4*)(out + o) = make_float4(hv4[0], hv4[1], hv4[2], hv4[3]);
                *(float4*)(out + (size_t)BATCH * SOUT * NB * HID + o)
                    = make_float4(ch4[0], ch4[1], ch4[2], ch4[3]);
            }
        }
    }
}

// ---------------------------------------------------------------------------
extern "C" void kernel_launch(void* const* d_in, const int* in_sizes, int n_in,
                              void* d_out, int out_size, void* d_ws, size_t ws_size,
                              hipStream_t stream) {
    const float* hid  = (const float*)d_in[0];
    const float* cel  = (const float*)d_in[1];
    const float* gt   = (const float*)d_in[2];
    // d_in[3] global_s_state: unused by the reference
    const float* p    = (const float*)d_in[4];
    const float* U    = (const float*)d_in[5];
    const float* Wt   = (const float*)d_in[6];
    const float* Ws   = (const float*)d_in[7];
    const float* bias = (const float*)d_in[8];
    float* out = (float*)d_out;

    char* cur_ = (char*)d_ws;
    auto carve = [&](size_t bytes) -> void* {
        void* r = cur_; cur_ += (bytes + 255) & ~(size_t)255; return r;
    };
    const size_t NPBH = (size_t)NB * BATCH * HID;
    unsigned short* wpack = (unsigned short*)carve((size_t)13271040 * 16); // 212 MB
    unsigned short* pb    = (unsigned short*)carve((size_t)SOUT * NB * BATCH * HID * 2);
    unsigned short* hp_b  = (unsigned short*)carve(2 * NPBH * 2);
    float*          cp_f  = (float*)carve(2 * NPBH * 4);
    unsigned short* bh_b  = (unsigned short*)carve((size_t)BATCH * HID * 2);
    float*          bc_f  = (float*)carve((size_t)BATCH * HID * 4);
    unsigned short* h_sl  = (unsigned short*)carve(4 * NPBH * 2);
    float*          c_sl  = (float*)carve(4 * NPBH * 4);

    prologue_kernel<<<NWU_BLK + NPU_BLK + NMU_BLK, 256, 0, stream>>>(
        U, Wt, Ws, p, hid, cel, gt, wpack, pb, hp_b, cp_f);
    init_bounds_kernel<<<(BATCH * HID + 255) / 256, 256, 0, stream>>>(
        hp_b, cp_f, bh_b, bc_f);

    auto cnt = [](int dg) {
        int lo = dg - (SOUT - 1); if (lo < 0) lo = 0;
        int hi = (dg < NB - 1) ? dg : NB - 1;
        return hi - lo + 1;
    };
    for (int d = 0; d < SOUT + NB; ++d) {          // 34 dispatches
        int A0 = (d <= SOUT + NB - 2) ? cnt(d) : 0;
        int A1 = (d >= 1) ? cnt(d - 1) : 0;
        int cellBlocks = 12 * (A0 + A1);
        int packBase = 540 * d;
        int packTiles = (packBase < PACK_TOT)
                        ? ((PACK_TOT - packBase < 540) ? (PACK_TOT - packBase) : 540)
                        : 0;
        int packBlocks = (packTiles + 2) / 3;
        int pbF = d + 2;
        int pbBlocks = (pbF <= SOUT - 1) ? PB_BLKS : 0;
        int grid = cellBlocks + packBlocks + pbBlocks;
        cell_fused_kernel<<<grid, 960, 0, stream>>>(
            d, A0, cellBlocks, packBase, packBlocks, pbF,
            U, Wt, Ws, p, pb, wpack, bias, hp_b, cp_f, bh_b, bc_f,
            h_sl, c_sl, out);
    }
}

// Round 16
// 1198.159 us; speedup vs baseline: 1.6491x; 1.0011x over previous
//
#include <hip/hip_runtime.h>

#define BATCH 64
#define TIN   49
#define NB    24
#define HID   384
#define SOUT  10
#define NGATE 5

typedef __attribute__((ext_vector_type(4))) float f32x4;
typedef __attribute__((ext_vector_type(8))) short short8v;

__device__ __forceinline__ unsigned short f2bf(float f) {
    union { float f; unsigned u; } v; v.f = f;
    unsigned r = v.u + 0x7fffu + ((v.u >> 16) & 1u);   // round-nearest-even
    return (unsigned short)(r >> 16);
}
__device__ __forceinline__ float bf2f(unsigned short h) {
    union { unsigned u; float f; } v; v.u = ((unsigned)h) << 16; return v.f;
}

// upfront prologue ranges: pack_w bones{0,1} + pack_p frames{0,1} + init_means
#define NWU_BLK 360     // 4 cells (0,1,24,25) x 90 tiles
#define NPU_BLK 4608    // 2 frame-slices x 2304
#define NMU_BLK 576
// deferred pack_w: bones 2..23 = 22 bones x 180 tiles = 3960 tiles,
// packed inside cell dispatches d=0..7 (540 tiles = 3 bones per dispatch).
#define PACK_TOT 3960
#define PB_BLKS  16     // hybrid pb-converter blocks per dispatch

// ---------------------------------------------------------------------------
// Upfront prologue: only what dispatch 0 needs.
// wpack layout (short8 units): [(cell*12+t32)*5+g][kc=36][pair=2][lane=64]
// ---------------------------------------------------------------------------
__global__ __launch_bounds__(256) void prologue_kernel(
    const float* __restrict__ U, const float* __restrict__ Wt,
    const float* __restrict__ Ws, const float* __restrict__ p,
    const float* __restrict__ hid, const float* __restrict__ cel,
    const float* __restrict__ gt,
    unsigned short* __restrict__ wpack, unsigned short* __restrict__ pb,
    unsigned short* __restrict__ hp_b, float* __restrict__ cp_f)
{
    __shared__ unsigned short tile[64][390];
    int bx = blockIdx.x;
    if (bx < NWU_BLK) {
        int c4i = bx / 90;
        int cell = (c4i < 2) ? c4i : 22 + c4i;         // {0,1,24,25}
        int sub = bx % 90;
        int kb = sub % 6, m = (sub / 6) % 3, g = sub / 18;
        const float* W = (m == 0) ? U : (m == 1) ? Wt : Ws;
        const float* src = W + ((size_t)(cell * NGATE + g) * HID + kb * 64) * HID;
        int tid = threadIdx.x;
#pragma unroll
        for (int i = 0; i < 24; ++i) {
            int c = tid + i * 256;
            int row = c / 96, c4 = (c % 96) * 4;
            float4 v = *(const float4*)(src + (size_t)row * HID + c4);
            tile[row][c4 + 0] = f2bf(v.x);
            tile[row][c4 + 1] = f2bf(v.y);
            tile[row][c4 + 2] = f2bf(v.z);
            tile[row][c4 + 3] = f2bf(v.w);
        }
        __syncthreads();
        int lane = tid & 63, grp = tid >> 6;
#pragma unroll
        for (int uu = 0; uu < 12; ++uu) {
            int unit = grp * 12 + uu;                  // 0..47
            int pair = unit & 1, kc2 = (unit >> 1) & 1, t32 = unit >> 2;
            int kl = kc2 * 32 + (lane >> 4) * 8;
            int cl = t32 * 32 + pair * 16 + (lane & 15);
            unsigned short o[8];
#pragma unroll
            for (int jj = 0; jj < 8; ++jj) o[jj] = tile[kl + jj][cl];
            int kc = m * 12 + kb * 2 + kc2;
            size_t dst = ((size_t)((cell * 12 + t32) * NGATE + g) * 72
                          + kc * 2 + pair) * 64 + lane;
            *(short8v*)(wpack + dst * 8) = *(const short8v*)o;
        }
    } else if (bx < NWU_BLK + NPU_BLK) {
        // p f32 [B][SOUT][NB][H] -> bf16 [SOUT][NB][B][H], frames 0..1 only
        size_t idx = (size_t)(bx - NWU_BLK) * 256 + threadIdx.x;
        int h = (int)(idx % HID);
        size_t q = idx / HID;
        int b = (int)(q % BATCH); q /= BATCH;
        int n = (int)(q % NB); q /= NB;
        int f = (int)q;                                // 0 or 1
        pb[idx] = f2bf(p[((size_t)(b * SOUT + f) * NB + n) * HID + h]);
    } else {
        // temporal means -> hp (bf16) + cp (f32), layout [r][n][b][h]
        // 2-way t-unroll with independent partial accumulators: doubles
        // loads-in-flight per thread (this section runs at 5.3/6.3 TB/s,
        // latency-limited at 2.25 blocks/CU).
        int idx = (bx - NWU_BLK - NPU_BLK) * 256 + threadIdx.x;
        const int total4 = NB * BATCH * HID / 4;
        if (idx >= total4) return;
        const int H4 = HID / 4;
        int h = (idx % H4) * 4;
        int b = (idx / H4) % BATCH;
        int n = idx / (H4 * BATCH);
        const int fs4 = NB * HID / 4;
        const float4* ph = (const float4*)(hid + ((size_t)b * TIN * NB + n) * HID + h);
        const float4* pc = (const float4*)(cel + ((size_t)b * TIN * NB + n) * HID + h);
        float sh0[4] = {0,0,0,0}, sh1[4] = {0,0,0,0};
        float sc0[4] = {0,0,0,0}, sc1[4] = {0,0,0,0};
        for (int t = 0; t < 48; t += 2) {
            float4 vh0 = ph[(size_t)t * fs4];
            float4 vh1 = ph[(size_t)(t + 1) * fs4];
            float4 vc0 = pc[(size_t)t * fs4];
            float4 vc1 = pc[(size_t)(t + 1) * fs4];
            sh0[0] += vh0.x; sh0[1] += vh0.y; sh0[2] += vh0.z; sh0[3] += vh0.w;
            sh1[0] += vh1.x; sh1[1] += vh1.y; sh1[2] += vh1.z; sh1[3] += vh1.w;
            sc0[0] += vc0.x; sc0[1] += vc0.y; sc0[2] += vc0.z; sc0[3] += vc0.w;
            sc1[0] += vc1.x; sc1[1] += vc1.y; sc1[2] += vc1.z; sc1[3] += vc1.w;
        }
        {
            float4 vh = ph[(size_t)48 * fs4];
            float4 vc = pc[(size_t)48 * fs4];
            sh0[0] += vh.x; sh0[1] += vh.y; sh0[2] += vh.z; sh0[3] += vh.w;
            sc0[0] += vc.x; sc0[1] += vc.y; sc0[2] += vc.z; sc0[3] += vc.w;
        }
        float sh[4], sc[4];
#pragma unroll
        for (int j = 0; j < 4; ++j) { sh[j] = sh0[j] + sh1[j]; sc[j] = sc0[j] + sc1[j]; }
        float4 g4 = *(const float4*)(gt + ((size_t)b * NB + n) * HID + h);
        const float* g_ = (const float*)&g4;
        unsigned short o0[4], o1[4];
        float c0[4];
#pragma unroll
        for (int j = 0; j < 4; ++j) {
            o0[j] = f2bf(sh[j] / TIN);
            o1[j] = f2bf((g_[j] + sh[j]) / (TIN + 1));
            c0[j] = sc[j] / TIN;
        }
        size_t base = (size_t)idx * 4;
        const size_t tot = (size_t)NB * BATCH * HID;
        *(uint2*)(hp_b + base)       = *(const uint2*)o0;
        *(uint2*)(hp_b + tot + base) = *(const uint2*)o1;
        *(float4*)(cp_f + base)       = make_float4(c0[0], c0[1], c0[2], c0[3]);
        *(float4*)(cp_f + tot + base) = make_float4(c0[0], c0[1], c0[2], c0[3]);
    }
}

// spatial boundary: mean over bones of the r=0 init states
__global__ void init_bounds_kernel(const unsigned short* __restrict__ hp_b,
                                   const float* __restrict__ cp_f,
                                   unsigned short* __restrict__ bh_b,
                                   float* __restrict__ bc_f) {
    int idx = blockIdx.x * blockDim.x + threadIdx.x;       // BATCH*HID
    if (idx >= BATCH * HID) return;
    float sh = 0.f, sc = 0.f;
    for (int n = 0; n < NB; ++n) {
        sh += bf2f(hp_b[(size_t)n * BATCH * HID + idx]);
        sc += cp_f[(size_t)n * BATCH * HID + idx];
    }
    bh_b[idx] = f2bf(sh / NB);
    bc_f[idx] = sc / NB;
}

// ---------------------------------------------------------------------------
// Hybrid wavefront kernel. Block ranges:
//   [0, cellBlocks)                : r11 cell path (verbatim; t=bx%12, y=bx/12)
//   [cellBlocks, +packBlocks)      : deferred pack_w, 3 tiles per 960-block
//   [.., +pbBlocks)                : pack_p slice f = pbF
// Deadlines: bone n packed in dispatch <= n-1 (schedule: bones {2+3d..4+3d}
// at dispatch d); pb slice f produced at dispatch f-2. Dispatch boundaries
// provide the ordering -- no atomics.
// ---------------------------------------------------------------------------
union SMem {
    unsigned short A[3][64][392];        // 150,528 B (cell path)
    float gl[3][NGATE][64][35];          // aliases A after compute (cell path)
    unsigned short tile3[3][64][390];    // 149,760 B (pack path)
};

__global__ __launch_bounds__(960) void cell_fused_kernel(
    int d, int A0, int cellBlocks, int packBase, int packBlocks, int pbF,
    const float* __restrict__ U, const float* __restrict__ Wt,
    const float* __restrict__ Ws, const float* __restrict__ p,
    unsigned short* __restrict__ pb,
    unsigned short* __restrict__ wpack,
    const float* __restrict__ bias,
    const unsigned short* __restrict__ hp_b,
    const float* __restrict__ cp_f,
    const unsigned short* __restrict__ bh_b,
    const float* __restrict__ bc_f,
    unsigned short* __restrict__ h_sl,   // [par][r][NB][64][384] bf16
    float* __restrict__ c_sl,            // same shape f32
    float* __restrict__ out)
{
    __shared__ SMem sm;
    const int bx = (int)blockIdx.x;
    const int tid = threadIdx.x;

    if (bx >= cellBlocks) {
        if (bx < cellBlocks + packBlocks) {
            // ---------------- deferred pack_w path ----------------
            const int sub3 = tid >> 8;                 // 0..3 (3 active)
            const int stid = tid & 255;
            int pt = packBase + (bx - cellBlocks) * 3 + sub3;
            bool act = (sub3 < 3) && (pt < PACK_TOT);
            int cell = 0, g = 0, m = 0, kb = 0;
            const float* src = U;
            if (act) {
                int bone = 2 + pt / 180;
                int srem = pt % 180;
                cell = (srem / 90) * NB + bone;
                int sub = srem % 90;
                kb = sub % 6; m = (sub / 6) % 3; g = sub / 18;
                const float* W = (m == 0) ? U : (m == 1) ? Wt : Ws;
                src = W + ((size_t)(cell * NGATE + g) * HID + kb * 64) * HID;
            }
            if (act) {
#pragma unroll
                for (int i = 0; i < 24; ++i) {
                    int c = stid + i * 256;
                    int row = c / 96, c4 = (c % 96) * 4;
                    float4 v = *(const float4*)(src + (size_t)row * HID + c4);
                    sm.tile3[sub3][row][c4 + 0] = f2bf(v.x);
                    sm.tile3[sub3][row][c4 + 1] = f2bf(v.y);
                    sm.tile3[sub3][row][c4 + 2] = f2bf(v.z);
                    sm.tile3[sub3][row][c4 + 3] = f2bf(v.w);
                }
            }
            __syncthreads();
            if (act) {
                int lane = stid & 63, grp = stid >> 6;
#pragma unroll
                for (int uu = 0; uu < 12; ++uu) {
                    int unit = grp * 12 + uu;
                    int pair = unit & 1, kc2 = (unit >> 1) & 1, t32 = unit >> 2;
                    int kl = kc2 * 32 + (lane >> 4) * 8;
                    int cl = t32 * 32 + pair * 16 + (lane & 15);
                    unsigned short o[8];
#pragma unroll
                    for (int jj = 0; jj < 8; ++jj) o[jj] = sm.tile3[sub3][kl + jj][cl];
                    int kc = m * 12 + kb * 2 + kc2;
                    size_t dst = ((size_t)((cell * 12 + t32) * NGATE + g) * 72
                                  + kc * 2 + pair) * 64 + lane;
                    *(short8v*)(wpack + dst * 8) = *(const short8v*)o;
                }
            }
        } else {
            // ---------------- deferred pack_p path (slice pbF) ----------------
            const int f = pbF;
            int wbase = (bx - cellBlocks - packBlocks) * 960 + tid;
            for (int w = wbase; w < NB * BATCH * HID / 4; w += PB_BLKS * 960) {
                int l = w * 4;
                int n = l / (BATCH * HID);
                int rem = l - n * (BATCH * HID);
                int b = rem / HID;
                int h = rem - b * HID;
                float4 v = *(const float4*)(p + ((size_t)(b * SOUT + f) * NB + n) * HID + h);
                unsigned short o[4] = { f2bf(v.x), f2bf(v.y), f2bf(v.z), f2bf(v.w) };
                *(uint2*)(pb + (size_t)f * NB * BATCH * HID + l) = *(const uint2*)o;
            }
        }
        return;
    }

    // ======================= r11 cell path (verbatim) =======================
    const int t = bx % 12;               // 32-col tile, 0..11
    int y = bx / 12;
    int rstep, dg;
    if (y < A0) { rstep = 0; dg = d; }
    else        { rstep = 1; dg = d - 1; y -= A0; }
    int lo = dg - (SOUT - 1); if (lo < 0) lo = 0;
    const int n = lo + y;
    const int f = dg - n;
    const int cur = dg & 1, prv = cur ^ 1;
    const int wv   = tid >> 6;
    const int gate = wv % NGATE;
    const int m    = wv / NGATE;         // source 0..2
    const int lane = tid & 63;
    const int S = BATCH * HID;
    const int cell = rstep * NB + n;

    const unsigned short *xb, *htb, *hsb;
    const float *ctb, *csb;
    if (rstep == 0) {
        xb  = pb + (size_t)(f * NB + n) * S;
        htb = f ? h_sl + (size_t)((prv * 2 + 0) * NB + n) * S : hp_b + (size_t)n * S;
        hsb = n ? h_sl + (size_t)((prv * 2 + 0) * NB + n - 1) * S : bh_b;
        ctb = f ? c_sl + (size_t)((prv * 2 + 0) * NB + n) * S : cp_f + (size_t)n * S;
        csb = n ? c_sl + (size_t)((prv * 2 + 0) * NB + n - 1) * S : bc_f;
    } else {
        xb  = h_sl + (size_t)((cur * 2 + 0) * NB + n) * S;   // h0 of this cell
        htb = f ? h_sl + (size_t)((prv * 2 + 1) * NB + n) * S
                : hp_b + (size_t)(NB + n) * S;
        hsb = n ? h_sl + (size_t)((prv * 2 + 1) * NB + n - 1) * S : bh_b;
        ctb = f ? c_sl + (size_t)((prv * 2 + 1) * NB + n) * S
                : cp_f + (size_t)(NB + n) * S;
        csb = n ? c_sl + (size_t)((prv * 2 + 1) * NB + n - 1) * S : bc_f;
    }

    const short8v* wp = (const short8v*)wpack
        + (size_t)((cell * 12 + t) * NGATE + gate) * (36 * 2 * 64);
    const short8v* wbm = wp + (size_t)(m * 24) * 64 + lane;

    // ---- hoist epilogue cell-state loads
    const int eb = tid & 63;
    const int ecq = (tid >> 6) & 3;
    float4 cth[2], csh[2];
    if (tid < 256) {
#pragma unroll
        for (int h = 0; h < 2; ++h) {
            int colg = t * 32 + h * 16 + ecq * 4;
            cth[h] = *(const float4*)(ctb + (size_t)eb * HID + colg);
            csh[h] = *(const float4*)(csb + (size_t)eb * HID + colg);
        }
    }

    // ---- stage all 3 sources up-front: 3 x 3072 16B-chunks, 960 threads
    uint4 streg[12];
#pragma unroll
    for (int s = 0; s < 3; ++s) {
        const unsigned short* sp = (s == 0) ? xb : (s == 1) ? htb : hsb;
#pragma unroll
        for (int i = 0; i < 4; ++i) {
            int c = tid + i * 960;
            if (i < 3 || c < 3072) {
                int row = c / 48, cc = c - row * 48;
                streg[s * 4 + i] = *(const uint4*)(sp + (size_t)row * HID + cc * 8);
            }
        }
    }
#pragma unroll
    for (int s = 0; s < 3; ++s) {
#pragma unroll
        for (int i = 0; i < 4; ++i) {
            int c = tid + i * 960;
            if (i < 3 || c < 3072) {
                int row = c / 48, cc = c - row * 48;
                *(uint4*)&sm.A[s][row][cc * 8] = streg[s * 4 + i];
            }
        }
    }

    // ---- preload rolling B window (in flight across the barrier)
    short8v bufB[3][2];
#pragma unroll
    for (int j = 0; j < 3; ++j) {
        bufB[j][0] = wbm[(size_t)j * 128];
        bufB[j][1] = wbm[(size_t)j * 128 + 64];
    }
    __syncthreads();                      // barrier 1: A staged

    f32x4 acc[2][4];
#pragma unroll
    for (int pr = 0; pr < 2; ++pr)
#pragma unroll
        for (int q2 = 0; q2 < 4; ++q2) acc[pr][q2] = (f32x4){0, 0, 0, 0};

    const int arow = lane & 15;
    const int akg  = (lane >> 4) * 8;

#pragma unroll
    for (int j = 0; j < 12; ++j) {
        const int koff = j * 32 + akg;
        short8v a[4];
#pragma unroll
        for (int q2 = 0; q2 < 4; ++q2)
            a[q2] = *(const short8v*)&sm.A[m][arow + q2 * 16][koff];
        const int sl = j % 3;
#pragma unroll
        for (int q2 = 0; q2 < 4; ++q2) {
            acc[0][q2] = __builtin_amdgcn_mfma_f32_16x16x32_bf16(a[q2], bufB[sl][0], acc[0][q2], 0, 0, 0);
            acc[1][q2] = __builtin_amdgcn_mfma_f32_16x16x32_bf16(a[q2], bufB[sl][1], acc[1][q2], 0, 0, 0);
        }
        if (j < 9) {
            bufB[sl][0] = wbm[(size_t)(j + 3) * 128];
            bufB[sl][1] = wbm[(size_t)(j + 3) * 128 + 64];
        }
    }
    __syncthreads();                      // barrier 2: A reads done; gl may alias

    // ---- gate exchange: each wave owns plane gl[m][gate]
#pragma unroll
    for (int pr = 0; pr < 2; ++pr)
#pragma unroll
        for (int q2 = 0; q2 < 4; ++q2)
#pragma unroll
            for (int i = 0; i < 4; ++i)
                sm.gl[m][gate][q2 * 16 + (lane >> 4) * 4 + i][pr * 16 + (lane & 15)]
                    = acc[pr][q2][i];
    __syncthreads();                      // barrier 3: planes visible

    // ---- fused epilogue (256 threads)
    if (tid < 256) {
        size_t dbase = (size_t)((cur * 2 + rstep) * NB + n) * S + (size_t)eb * HID;
        const float* bbase = bias + (size_t)cell * NGATE * HID;
#pragma unroll
        for (int h = 0; h < 2; ++h) {
            int cloc = h * 16 + ecq * 4;
            int colg = t * 32 + cloc;
            const float* ct_ = (const float*)&cth[h];
            const float* cs_ = (const float*)&csh[h];
            float hv4[4], ch4[4];
            unsigned short hb4[4];
#pragma unroll
            for (int cc = 0; cc < 4; ++cc) {
                int c = cloc + cc;
                float gi  = sm.gl[0][0][eb][c] + sm.gl[1][0][eb][c] + sm.gl[2][0][eb][c] + bbase[0 * HID + colg + cc];
                float gfs = sm.gl[0][1][eb][c] + sm.gl[1][1][eb][c] + sm.gl[2][1][eb][c] + bbase[1 * HID + colg + cc];
                float gft = sm.gl[0][2][eb][c] + sm.gl[1][2][eb][c] + sm.gl[2][2][eb][c] + bbase[2 * HID + colg + cc];
                float go  = sm.gl[0][3][eb][c] + sm.gl[1][3][eb][c] + sm.gl[2][3][eb][c] + bbase[3 * HID + colg + cc];
                float gc  = sm.gl[0][4][eb][c] + sm.gl[1][4][eb][c] + sm.gl[2][4][eb][c] + bbase[4 * HID + colg + cc];
                float i_n = 1.f / (1.f + __expf(-gi));
                float f_s = 1.f / (1.f + __expf(-gfs));
                float f_t = 1.f / (1.f + __expf(-gft));
                float o_n = 1.f / (1.f + __expf(-go));
                float c_n = tanhf(gc);
                float ch  = i_n * c_n + f_t * ct_[cc] + f_s * cs_[cc];
                float hv  = o_n * tanhf(ch);
                hv4[cc] = hv; ch4[cc] = ch; hb4[cc] = f2bf(hv);
            }
            *(uint2*)(h_sl + dbase + colg) = *(const uint2*)hb4;
            *(float4*)(c_sl + dbase + colg) = make_float4(ch4[0], ch4[1], ch4[2], ch4[3]);
            if (rstep == 1) {
                size_t o = ((size_t)(eb * SOUT + f) * NB + n) * HID + colg;
                *(float4*)(out + o) = make_float4(hv4[0], hv4[1], hv4[2], hv4[3]);
                *(float4*)(out + (size_t)BATCH * SOUT * NB * HID + o)
                    = make_float4(ch4[0], ch4[1], ch4[2], ch4[3]);
            }
        }
    }
}

// ---------------------------------------------------------------------------
extern "C" void kernel_launch(void* const* d_in, const int* in_sizes, int n_in,
                              void* d_out, int out_size, void* d_ws, size_t ws_size,
                              hipStream_t stream) {
    const float* hid  = (const float*)d_in[0];
    const float* cel  = (const float*)d_in[1];
    const float* gt   = (const float*)d_in[2];
    // d_in[3] global_s_state: unused by the reference
    const float* p    = (const float*)d_in[4];
    const float* U    = (const float*)d_in[5];
    const float* Wt   = (const float*)d_in[6];
    const float* Ws   = (const float*)d_in[7];
    const float* bias = (const float*)d_in[8];
    float* out = (float*)d_out;

    char* cur_ = (char*)d_ws;
    auto carve = [&](size_t bytes) -> void* {
        void* r = cur_; cur_ += (bytes + 255) & ~(size_t)255; return r;
    };
    const size_t NPBH = (size_t)NB * BATCH * HID;
    unsigned short* wpack = (unsigned short*)carve((size_t)13271040 * 16); // 212 MB
    unsigned short* pb    = (unsigned short*)carve((size_t)SOUT * NB * BATCH * HID * 2);
    unsigned short* hp_b  = (unsigned short*)carve(2 * NPBH * 2);
    float*          cp_f  = (float*)carve(2 * NPBH * 4);
    unsigned short* bh_b  = (unsigned short*)carve((size_t)BATCH * HID * 2);
    float*          bc_f  = (float*)carve((size_t)BATCH * HID * 4);
    unsigned short* h_sl  = (unsigned short*)carve(4 * NPBH * 2);
    float*          c_sl  = (float*)carve(4 * NPBH * 4);

    prologue_kernel<<<NWU_BLK + NPU_BLK + NMU_BLK, 256, 0, stream>>>(
        U, Wt, Ws, p, hid, cel, gt, wpack, pb, hp_b, cp_f);
    init_bounds_kernel<<<(BATCH * HID + 255) / 256, 256, 0, stream>>>(
        hp_b, cp_f, bh_b, bc_f);

    auto cnt = [](int dg) {
        int lo = dg - (SOUT - 1); if (lo < 0) lo = 0;
        int hi = (dg < NB - 1) ? dg : NB - 1;
        return hi - lo + 1;
    };
    for (int d = 0; d < SOUT + NB; ++d) {          // 34 dispatches
        int A0 = (d <= SOUT + NB - 2) ? cnt(d) : 0;
        int A1 = (d >= 1) ? cnt(d - 1) : 0;
        int cellBlocks = 12 * (A0 + A1);
        int packBase = 540 * d;
        int packTiles = (packBase < PACK_TOT)
                        ? ((PACK_TOT - packBase < 540) ? (PACK_TOT - packBase) : 540)
                        : 0;
        int packBlocks = (packTiles + 2) / 3;
        int pbF = d + 2;
        int pbBlocks = (pbF <= SOUT - 1) ? PB_BLKS : 0;
        int grid = cellBlocks + packBlocks + pbBlocks;
        cell_fused_kernel<<<grid, 960, 0, stream>>>(
            d, A0, cellBlocks, packBase, packBlocks, pbF,
            U, Wt, Ws, p, pb, wpack, bias, hp_b, cp_f, bh_b, bc_f,
            h_sl, c_sl, out);
    }
}